// Round 1
// baseline (463.620 us; speedup 1.0000x reference)
//
#include <hip/hip_runtime.h>

// HMM trajectory forward pass.
// One wave (64 lanes) per batch element; lane k holds state k (b==64).
// Recurrence rewritten rank-1+diag -> O(b)/step, run in scaled probability
// space: p[k] ~ exp(f[k] - C), renormalized by S each step.
__global__ __launch_bounds__(64)
void hmm_fwd(const float* __restrict__ stop,     // (B, T+1, 64, 2)
             const float* __restrict__ start,    // (B, T+1, 64)
             const float* __restrict__ act,      // (B, T+1, 64, A)
             const int*   __restrict__ actions,  // (B, T)
             const int*   __restrict__ lengths,  // (B,)
             float* __restrict__ out,            // scalar
             int T, int A)
{
    const int bi   = blockIdx.x;
    const int lane = threadIdx.x;   // state index 0..63
    const int Tp1  = T + 1;
    const int NB   = 64;

    const float* stopB  = stop  + (size_t)bi * Tp1 * NB * 2;
    const float* startB = start + (size_t)bi * Tp1 * NB;
    const float* actB   = act   + (size_t)bi * Tp1 * NB * A;
    const int*   actsB  = actions + (size_t)bi * T;

    const int L = lengths[bi];      // wave-uniform

    float p  = (lane == 0) ? 1.0f : 0.0f;  // p0 = e_0  (f0[0]=0, else -inf)
    float C2 = 0.0f;                        // accumulated log2-scale

    // distance-1 prefetch
    float2 so_n = make_float2(0.0f, 0.0f);
    float  st_n = 0.0f, ch_n = 0.0f;
    if (L > 1) {
        so_n = *(const float2*)(stopB + ((size_t)1 * NB + lane) * 2);
        st_n = startB[1 * NB + lane];
        ch_n = actB[((size_t)1 * NB + lane) * A + actsB[1]];
    }

    for (int t = 1; t < L; ++t) {
        const float2 so_c = so_n;           // (beta, ombeta) at t
        const float  st_c = st_n;
        const float  ch_c = ch_n;
        if (t + 1 < L) {                    // issue next loads before the chain
            so_n = *(const float2*)(stopB + ((size_t)(t + 1) * NB + lane) * 2);
            st_n = startB[(t + 1) * NB + lane];
            ch_n = actB[((size_t)(t + 1) * NB + lane) * A + actsB[t + 1]];
        }
        const float Bv = __expf(so_c.x);        // exp(beta)
        const float A1 = __expf(ch_c + st_c);   // exp(chosen + start)
        const float A2 = __expf(ch_c + so_c.y); // exp(chosen + continue)

        float s = p * Bv;                       // S = sum_j p[j] exp(beta[j])
        #pragma unroll
        for (int m = 1; m < 64; m <<= 1)
            s += __shfl_xor(s, m, 64);

        const float tmp = A2 * p;               // off critical path vs reduction
        const float inv = __builtin_amdgcn_rcpf(s);
        C2 += __log2f(s);
        p = fmaf(tmp, inv, A1);
    }

    // total = C + log( sum_k p[k] * exp(beta[L,k]) )
    const float bl = stopB[((size_t)L * NB + lane) * 2];
    float s = p * __expf(bl);
    #pragma unroll
    for (int m = 1; m < 64; m <<= 1)
        s += __shfl_xor(s, m, 64);

    const float total = 0.69314718055994531f * (C2 + __log2f(s));
    if (lane == 0)
        atomicAdd(out, -total);   // out = -sum_b total_b
}

extern "C" void kernel_launch(void* const* d_in, const int* in_sizes, int n_in,
                              void* d_out, int out_size, void* d_ws, size_t ws_size,
                              hipStream_t stream)
{
    const float* stop    = (const float*)d_in[0];
    const float* start   = (const float*)d_in[1];
    const float* act     = (const float*)d_in[2];
    const int*   actions = (const int*)d_in[3];
    const int*   lengths = (const int*)d_in[4];
    float* out = (float*)d_out;

    const int B   = in_sizes[4];
    const int T   = in_sizes[3] / B;
    const int Tp1 = T + 1;
    const int A   = in_sizes[2] / (B * Tp1 * 64);

    hipMemsetAsync(out, 0, sizeof(float), stream);
    hmm_fwd<<<dim3(B), dim3(64), 0, stream>>>(stop, start, act, actions, lengths,
                                              out, T, A);
}

// Round 3
// 258.730 us; speedup vs baseline: 1.7919x; 1.7919x over previous
//
#include <hip/hip_runtime.h>

// HMM trajectory forward pass, rank-1+diag rewrite, scaled-probability space.
// One wave (64 lanes = 64 states) per batch element.
// R3: same as R2 but DPP ctrl/rmask as template (immediate) args.

#define CH 16

template <int CTRL, int RMASK>
__device__ __forceinline__ float dpp_add(float x) {
    int yi = __builtin_amdgcn_update_dpp(
        0, __builtin_bit_cast(int, x), CTRL, RMASK, 0xf, true);
    return x + __builtin_bit_cast(float, yi);
}

// sum over all 64 lanes, result returned as wave-uniform scalar
__device__ __forceinline__ float wave_sum64(float x) {
    x = dpp_add<0x111, 0xf>(x);   // row_shr:1
    x = dpp_add<0x112, 0xf>(x);   // row_shr:2
    x = dpp_add<0x114, 0xf>(x);   // row_shr:4
    x = dpp_add<0x118, 0xf>(x);   // row_shr:8
    x = dpp_add<0x142, 0xa>(x);   // row_bcast:15 (rows 1,3)
    x = dpp_add<0x143, 0xc>(x);   // row_bcast:31 (row 3)
    return __builtin_bit_cast(float,
        __builtin_amdgcn_readlane(__builtin_bit_cast(int, x), 63));
}

__global__ __launch_bounds__(64)
void hmm_fwd(const float* __restrict__ stop,     // (B, T+1, 64, 2)
             const float* __restrict__ start,    // (B, T+1, 64)
             const float* __restrict__ act,      // (B, T+1, 64, A)
             const int*   __restrict__ actions,  // (B, T)
             const int*   __restrict__ lengths,  // (B,)
             float* __restrict__ out,            // scalar
             int T, int A)
{
    const int bi   = blockIdx.x;
    const int lane = threadIdx.x;
    const int Tp1  = T + 1;
    const int NB   = 64;

    const float* stopP  = stop  + (size_t)bi * Tp1 * NB * 2 + lane * 2;
    const float* startP = start + (size_t)bi * Tp1 * NB     + lane;
    const float* actP   = act   + (size_t)bi * Tp1 * NB * A + lane * A;
    const int*   actsB  = actions + (size_t)bi * T;

    const int L = lengths[bi];            // wave-uniform
    const int rowA = NB * A;

    // Stage this batch's actions into LDS once (single wave: no barrier).
    __shared__ int actsL[1024];
    for (int i = lane; i < T; i += 64) actsL[i] = actsB[i];

    float p  = (lane == 0) ? 1.0f : 0.0f;
    float C2 = 0.0f;

    float bufB[2][CH], bufO[2][CH], bufS[2][CH], bufC[2][CH];
    int   actsR[2][CH];

#define LOAD_ACTS(slot, cbase) do {                                          \
    _Pragma("unroll")                                                        \
    for (int i = 0; i < CH; ++i) {                                           \
        int t = min((cbase) + i, L - 1);                                     \
        actsR[slot][i] = actsL[t];                                           \
    } } while (0)

#define LOAD_DATA(slot, cbase) do {                                          \
    _Pragma("unroll")                                                        \
    for (int i = 0; i < CH; ++i) {                                           \
        int t = min((cbase) + i, L - 1);                                     \
        float2 so = *(const float2*)(stopP + (size_t)t * (NB * 2));          \
        bufB[slot][i] = so.x;                                                \
        bufO[slot][i] = so.y;                                                \
        bufS[slot][i] = startP[(size_t)t * NB];                              \
        bufC[slot][i] = actP[(size_t)t * rowA + actsR[slot][i]];             \
    } } while (0)

#define STEP(slot, i) {                                                      \
    const float Bv  = __expf(bufB[slot][i]);                                 \
    const float A1  = __expf(bufC[slot][i] + bufS[slot][i]);                 \
    const float A2e = __expf(bufC[slot][i] + bufO[slot][i]);                 \
    const float st  = wave_sum64(p * Bv);                                    \
    const float tmp = A2e * p;                                               \
    const float inv = __builtin_amdgcn_rcpf(st);                             \
    C2 += __log2f(st);                                                       \
    p = fmaf(tmp, inv, A1);                                                  \
}

#define COMPUTE(slot, cbase) do {                                            \
    _Pragma("unroll")                                                        \
    for (int i = 0; i < CH; ++i) {                                           \
        if ((cbase) + i < L) { STEP(slot, i) }                               \
    } } while (0)

    int base = 1;
    if (base < L) {
        LOAD_ACTS(0, base);
        LOAD_DATA(0, base);           // first chunk: latency exposed once
        LOAD_ACTS(1, base + CH);
        while (true) {
            LOAD_ACTS(0, base + 2 * CH);   // acts for chunk c+2 (slot 0)
            LOAD_DATA(1, base + CH);       // data for chunk c+1 (slot 1)
            COMPUTE(0, base);
            base += CH;
            if (base >= L) break;
            LOAD_ACTS(1, base + 2 * CH);
            LOAD_DATA(0, base + CH);
            COMPUTE(1, base);
            base += CH;
            if (base >= L) break;
        }
    }

    // total = C + log( sum_k p[k] * exp(beta[L,k]) )
    const float bl = stopP[(size_t)L * (NB * 2)];
    const float s  = wave_sum64(p * __expf(bl));

    const float total = 0.69314718055994531f * (C2 + __log2f(s));
    if (lane == 0)
        atomicAdd(out, -total);

#undef LOAD_ACTS
#undef LOAD_DATA
#undef STEP
#undef COMPUTE
}

extern "C" void kernel_launch(void* const* d_in, const int* in_sizes, int n_in,
                              void* d_out, int out_size, void* d_ws, size_t ws_size,
                              hipStream_t stream)
{
    const float* stop    = (const float*)d_in[0];
    const float* start   = (const float*)d_in[1];
    const float* act     = (const float*)d_in[2];
    const int*   actions = (const int*)d_in[3];
    const int*   lengths = (const int*)d_in[4];
    float* out = (float*)d_out;

    const int B   = in_sizes[4];
    const int T   = in_sizes[3] / B;
    const int Tp1 = T + 1;
    const int A   = in_sizes[2] / (B * Tp1 * 64);

    (void)hipMemsetAsync(out, 0, sizeof(float), stream);
    hmm_fwd<<<dim3(B), dim3(64), 0, stream>>>(stop, start, act, actions, lengths,
                                              out, T, A);
}